// Round 9
// baseline (250.573 us; speedup 1.0000x reference)
//
#include <hip/hip_runtime.h>

typedef unsigned short u16;
typedef unsigned int u32;
typedef unsigned long long u64;
typedef float f32x4 __attribute__((ext_vector_type(4)));
typedef __bf16 bf16x8 __attribute__((ext_vector_type(8)));

// f32 -> bf16 round-to-nearest-even (scalar)
__device__ __forceinline__ u16 f2bf(float f) {
  unsigned u = __float_as_uint(f);
  unsigned r = u + 0x7fffu + ((u >> 16) & 1u);
  return (u16)(r >> 16);
}
// packed f32 pair -> 2x bf16 in one u32 (lo = first arg)
__device__ __forceinline__ u32 cvt_pk_bf16(float lo, float hi) {
  u32 r;
  asm("v_cvt_pk_bf16_f32 %0, %1, %2" : "=v"(r) : "v"(lo), "v"(hi));
  return r;
}
// hardware 2^x
__device__ __forceinline__ float exp2_hw(float x) {
  float r;
  asm("v_exp_f32 %0, %1" : "=v"(r) : "v"(x));
  return r;
}
__device__ __forceinline__ bf16x8 f32x8_to_bf16x8(float4 a, float4 b) {
  union { u32 u[4]; bf16x8 v; } t;
  t.u[0] = cvt_pk_bf16(a.x, a.y);
  t.u[1] = cvt_pk_bf16(a.z, a.w);
  t.u[2] = cvt_pk_bf16(b.x, b.y);
  t.u[3] = cvt_pk_bf16(b.z, b.w);
  return t.v;
}

// 1/sqrt(32) * log2(e)  — softmax scale folded with exp->exp2 conversion
#define QSCALE 0.25513936f

// ---------------------------------------------------------------------------
// proj_kernel (unchanged, verified in R7): blocks 0..255 -> fused pooled K+V
// path, z-split; blocks 256..767 -> Q path (LDS-staged MFMA).
// Layouts: Qb[b][t][32], Kt[b][s][32], Vb[b][ch][4096].
// ---------------------------------------------------------------------------
__global__ __launch_bounds__(256) void proj_kernel(
    const float* __restrict__ x, const float* __restrict__ Wq, const float* __restrict__ bq,
    const float* __restrict__ Wk, const float* __restrict__ bk, const float* __restrict__ Wv,
    const float* __restrict__ bv, u16* __restrict__ Qb, u16* __restrict__ Kt,
    u16* __restrict__ Vb) {
  __shared__ __align__(16) u16 smem[24576];  // 48KB: xt(32KB)+wq(16KB) | xs(32KB)
  const int tid = threadIdx.x;
  const int lane = tid & 63, w = tid >> 6;
  const int l15 = lane & 15, l4 = lane >> 4;
  const int bi = blockIdx.x;
  const f32x4 zero = {0.f, 0.f, 0.f, 0.f};

  if (bi >= 256) {
    // ================= Q path (verified, LDS-staged) =================
    u16* xt = smem;          // [64 t][256 c] bf16, swizzled
    u16* wq = smem + 16384;  // [32 oc][256 c] bf16, swizzled, pre-scaled
    const int j = bi - 256;
    const int b = j >> 8, tb = j & 255;
    const float* xp = x + (size_t)b * 256 * 16384 + tb * 64;

    for (int i = tid; i < 4096; i += 256) {
      int oc = i >> 7, c0 = (i & 127) * 2;
      float2 f = *reinterpret_cast<const float2*>(Wq + oc * 256 + c0);
      u32 pk = cvt_pk_bf16(f.x * QSCALE, f.y * QSCALE);
      *reinterpret_cast<u32*>((char*)wq + oc * 512 + (((c0 >> 3) ^ (oc & 7)) * 16) +
                              (c0 & 7) * 2) = pk;
    }
#pragma unroll
    for (int rr = 0; rr < 4; ++rr) {
      int c = rr * 64 + (tid >> 2);
      int tch = (tid & 3) * 16;
      const float* src = xp + (size_t)c * 16384 + tch;
#pragma unroll
      for (int u = 0; u < 4; ++u) {
        float4 f = *reinterpret_cast<const float4*>(src + u * 4);
        int t = tch + u * 4;
        *reinterpret_cast<u16*>((char*)xt + (t + 0) * 512 + (((c >> 3) ^ ((t + 0) & 7)) * 16) + (c & 7) * 2) = f2bf(f.x);
        *reinterpret_cast<u16*>((char*)xt + (t + 1) * 512 + (((c >> 3) ^ ((t + 1) & 7)) * 16) + (c & 7) * 2) = f2bf(f.y);
        *reinterpret_cast<u16*>((char*)xt + (t + 2) * 512 + (((c >> 3) ^ ((t + 2) & 7)) * 16) + (c & 7) * 2) = f2bf(f.z);
        *reinterpret_cast<u16*>((char*)xt + (t + 3) * 512 + (((c >> 3) ^ ((t + 3) & 7)) * 16) + (c & 7) * 2) = f2bf(f.w);
      }
    }
    __syncthreads();

    f32x4 acc[2] = {zero, zero};
    const int tl = w * 16 + l15;
#pragma unroll
    for (int k = 0; k < 8; ++k) {
      bf16x8 bf = *reinterpret_cast<const bf16x8*>((char*)xt + tl * 512 +
                                                   (((k * 4 + l4) ^ (tl & 7)) * 16));
#pragma unroll
      for (int m = 0; m < 2; ++m) {
        int oc = m * 16 + l15;
        bf16x8 af = *reinterpret_cast<const bf16x8*>((char*)wq + oc * 512 +
                                                     (((k * 4 + l4) ^ (oc & 7)) * 16));
        acc[m] = __builtin_amdgcn_mfma_f32_16x16x32_bf16(af, bf, acc[m], 0, 0, 0);
      }
    }
    const int t = tb * 64 + tl;
#pragma unroll
    for (int m = 0; m < 2; ++m) {
      int oc0 = m * 16 + l4 * 4;
      u32 p0 = cvt_pk_bf16(acc[m][0] + bq[oc0] * QSCALE, acc[m][1] + bq[oc0 + 1] * QSCALE);
      u32 p1 = cvt_pk_bf16(acc[m][2] + bq[oc0 + 2] * QSCALE, acc[m][3] + bq[oc0 + 3] * QSCALE);
      u16* dst = Qb + ((size_t)b * 16384 + t) * 32 + oc0;
      *reinterpret_cast<u32*>(dst) = p0;
      *reinterpret_cast<u32*>(dst + 2) = p1;
    }
  } else {
    // ================= fused K+V path, z-split =================
    u16* xs = smem;  // pooled [64 s][256 c] bf16, swizzled
    const int b = bi >> 7, r2 = bi & 127;
    const int sy = r2 >> 1, z = r2 & 1;
    const int mb = z * 8;
    const float* xb = x + (size_t)b * 256 * 16384;

#pragma unroll
    for (int rr = 0; rr < 4; ++rr) {
      int c = rr * 64 + (tid >> 2);
      int f4base = (tid & 3) * 8;
      const float* r0 = xb + (size_t)c * 16384 + (size_t)sy * 256;
#pragma unroll
      for (int u = 0; u < 8; ++u) {
        int jj = f4base + u;
        float4 a = *reinterpret_cast<const float4*>(r0 + jj * 4);
        float4 d = *reinterpret_cast<const float4*>(r0 + 128 + jj * 4);
        float p0 = (a.x + a.y + d.x + d.y) * 0.25f;
        float p1 = (a.z + a.w + d.z + d.w) * 0.25f;
        int s0 = jj * 2;
        *reinterpret_cast<u16*>((char*)xs + (s0 + 0) * 512 + (((c >> 3) ^ ((s0 + 0) & 7)) * 16) + (c & 7) * 2) = f2bf(p0);
        *reinterpret_cast<u16*>((char*)xs + (s0 + 1) * 512 + (((c >> 3) ^ ((s0 + 1) & 7)) * 16) + (c & 7) * 2) = f2bf(p1);
      }
    }
    __syncthreads();

    f32x4 acc[10];
#pragma unroll
    for (int m = 0; m < 10; ++m) acc[m] = zero;
    const int sl = w * 16 + l15;
#pragma unroll
    for (int k = 0; k < 8; ++k) {
      bf16x8 bf = *reinterpret_cast<const bf16x8*>((char*)xs + sl * 512 +
                                                   (((k * 4 + l4) ^ (sl & 7)) * 16));
      if (z == 0) {
#pragma unroll
        for (int m = 0; m < 2; ++m) {
          const float* wr = Wk + (size_t)(m * 16 + l15) * 256 + k * 32 + l4 * 8;
          float4 fa = *reinterpret_cast<const float4*>(wr);
          float4 fb = *reinterpret_cast<const float4*>(wr + 4);
          acc[m] = __builtin_amdgcn_mfma_f32_16x16x32_bf16(f32x8_to_bf16x8(fa, fb), bf, acc[m], 0, 0, 0);
        }
      }
#pragma unroll
      for (int mm = 0; mm < 8; ++mm) {
        const float* wr = Wv + (size_t)((mb + mm) * 16 + l15) * 256 + k * 32 + l4 * 8;
        float4 fa = *reinterpret_cast<const float4*>(wr);
        float4 fb = *reinterpret_cast<const float4*>(wr + 4);
        acc[2 + mm] = __builtin_amdgcn_mfma_f32_16x16x32_bf16(f32x8_to_bf16x8(fa, fb), bf, acc[2 + mm], 0, 0, 0);
      }
    }
    if (z == 0) {
#pragma unroll
      for (int m = 0; m < 2; ++m) {
        int oc0 = m * 16 + l4 * 4;
        u32 p0 = cvt_pk_bf16(acc[m][0] + bk[oc0], acc[m][1] + bk[oc0 + 1]);
        u32 p1 = cvt_pk_bf16(acc[m][2] + bk[oc0 + 2], acc[m][3] + bk[oc0 + 3]);
        u16* dst = Kt + ((size_t)b * 4096 + sy * 64 + sl) * 32 + oc0;
        *reinterpret_cast<u32*>(dst) = p0;
        *reinterpret_cast<u32*>(dst + 2) = p1;
      }
    }
#pragma unroll
    for (int mm = 0; mm < 8; ++mm) {
#pragma unroll
      for (int r = 0; r < 4; ++r) {
        int oc = (mb + mm) * 16 + l4 * 4 + r;
        Vb[((size_t)b * 256 + oc) * 4096 + sy * 64 + sl] = f2bf(acc[2 + mm][r] + bv[oc]);
      }
    }
  }
}

// ---------------------------------------------------------------------------
// attn v9 = v8 with the vfr buffer bug fixed: vfr buffers are [2][4] (the
// wave covers 64 channels = 4 nt-tiles; v8's [2][2] caused OOB register-array
// reads -> NaN). All 8 V loads share ONE running voffset vo0 via 4
// loop-invariant nt-base pointers (nt stride = 16*8192 = 131072 B) and a
// +64 immediate for ks. Rest identical to v8:
//  - LDS lane-base regs + compile-time immediates, kt unrolled x2 (static cur)
//  - next-iter V/K loads issued at iteration TOP (pre-paid vmcnt drain)
//  - s_setprio(1) around the PV MFMA cluster.
// ---------------------------------------------------------------------------
__global__ __launch_bounds__(256, 2) void attn_kernel(
    const u16* __restrict__ Qb, const u16* __restrict__ Kt, const u16* __restrict__ Vb,
    const float* __restrict__ x, const float* __restrict__ gamma, float* __restrict__ out) {
  __shared__ __align__(16) u16 p_lds[2][128 * 64];  // 32KB (dbuf)
  __shared__ float lred[4][128];

  const int tid = threadIdx.x;
  const int lane = tid & 63, w = tid >> 6;
  const int l15 = lane & 15, l4 = lane >> 4, l7 = l15 & 7;
  const int raw = blockIdx.x;               // 0..511
  const int xcd = raw & 7, loc = raw >> 3;  // loc 0..63
  const int b = xcd >> 2;
  const int H = loc & 1;
  const int tt = (xcd & 3) * 32 + (loc >> 1);
  const int t0 = tt * 128;
  const int th = w >> 1, chh = w & 1;
  const int CHW = H * 128 + chh * 64;

  const u16* Qp = Qb + (size_t)(b * 16384 + t0) * 32;
  const u16* Kp = Kt + (size_t)b * 4096 * 32;
  const char* Kpc = (const char*)Kp;
  const char* Vpc = (const char*)(Vb + (size_t)b * 256 * 4096);
  // nt-base pointers: ch-tile stride = 16 ch * 8192 B
  const char* VpB0 = Vpc;
  const char* VpB1 = Vpc + 131072;
  const char* VpB2 = Vpc + 262144;
  const char* VpB3 = Vpc + 393216;

  // Q fragments (loop-invariant)
  bf16x8 qfr[8];
#pragma unroll
  for (int mt = 0; mt < 8; ++mt)
    qfr[mt] = *reinterpret_cast<const bf16x8*>(Qp + (size_t)(mt * 16 + l15) * 32 + l4 * 8);

  const int key = w * 16 + l15;
  const int pw_chunk = w * 2 + (l4 >> 1), pw_off = (l4 & 1) * 8;

  // ---- loop-invariant lane bases (LDS); valid since tok&7 == l7 ----
  char* pA0 = (char*)p_lds + (th * 64 + l15) * 128 + ((l4 ^ l7) * 16);
  char* pA1 = (char*)p_lds + (th * 64 + l15) * 128 + (((4 + l4) ^ l7) * 16);
  char* pW = (char*)p_lds + l15 * 128 + ((pw_chunk ^ l7) * 16) + pw_off;

  // ---- running byte-voffsets (32-bit) ----
  u32 vo0 = (u32)(CHW + l15) * 8192 + 128 + l4 * 16;  // V(kt=1), ks=0 (shared by all nt)
  u32 vok = 2 * 4096 + key * 64 + l4 * 16;            // K(kt=2)

  f32x4 acc[4][4] = {};
  float lsum[8] = {};
  const f32x4 zero = {0.f, 0.f, 0.f, 0.f};

  // ---- prologue: QK(0) + write buf0; load kfrA=K(1), vfrA=V(0) ----
  {
    bf16x8 k0 = *reinterpret_cast<const bf16x8*>(Kp + (size_t)key * 32 + l4 * 8);
#pragma unroll
    for (int mt = 0; mt < 8; ++mt) {
      f32x4 s = __builtin_amdgcn_mfma_f32_16x16x32_bf16(k0, qfr[mt], zero, 0, 0, 0);
      float p0 = exp2_hw(fminf(s[0], 28.f)), p1 = exp2_hw(fminf(s[1], 28.f));
      float p2 = exp2_hw(fminf(s[2], 28.f)), p3 = exp2_hw(fminf(s[3], 28.f));
      lsum[mt] += (p0 + p1) + (p2 + p3);
      *reinterpret_cast<u64*>(pW + mt * 2048) =
          (u64)cvt_pk_bf16(p0, p1) | ((u64)cvt_pk_bf16(p2, p3) << 32);
    }
  }
  bf16x8 kfrA = *reinterpret_cast<const bf16x8*>(Kpc + (4096 + key * 64 + l4 * 16));
  bf16x8 kfrB;
  bf16x8 vfrA[2][4], vfrB[2][4];
  vfrA[0][0] = *reinterpret_cast<const bf16x8*>(VpB0 + (vo0 - 128));
  vfrA[1][0] = *reinterpret_cast<const bf16x8*>(VpB0 + (vo0 - 128 + 64));
  vfrA[0][1] = *reinterpret_cast<const bf16x8*>(VpB1 + (vo0 - 128));
  vfrA[1][1] = *reinterpret_cast<const bf16x8*>(VpB1 + (vo0 - 128 + 64));
  vfrA[0][2] = *reinterpret_cast<const bf16x8*>(VpB2 + (vo0 - 128));
  vfrA[1][2] = *reinterpret_cast<const bf16x8*>(VpB2 + (vo0 - 128 + 64));
  vfrA[0][3] = *reinterpret_cast<const bf16x8*>(VpB3 + (vo0 - 128));
  vfrA[1][3] = *reinterpret_cast<const bf16x8*>(VpB3 + (vo0 - 128 + 64));
  __syncthreads();

#define ATTN_ITER(KT, CUR, VC, VN, KC, KN)                                               \
  {                                                                                      \
    /* afr ds_reads for P[CUR] (lane base + immediates) */                               \
    bf16x8 afr0[4], afr1[4];                                                             \
    _Pragma("unroll") for (int mt = 0; mt < 4; ++mt) {                                   \
      afr0[mt] = *reinterpret_cast<const bf16x8*>(pA0 + ((CUR)*16384 + mt * 2048));      \
      afr1[mt] = *reinterpret_cast<const bf16x8*>(pA1 + ((CUR)*16384 + mt * 2048));      \
    }                                                                                    \
    if ((KT) < 63) {                                                                     \
      /* issue next-iter V/K loads FIRST: drain happens under QK/exp/PV */               \
      VN[0][0] = *reinterpret_cast<const bf16x8*>(VpB0 + vo0);                           \
      VN[1][0] = *reinterpret_cast<const bf16x8*>(VpB0 + (vo0 + 64));                    \
      VN[0][1] = *reinterpret_cast<const bf16x8*>(VpB1 + vo0);                           \
      VN[1][1] = *reinterpret_cast<const bf16x8*>(VpB1 + (vo0 + 64));                    \
      VN[0][2] = *reinterpret_cast<const bf16x8*>(VpB2 + vo0);                           \
      VN[1][2] = *reinterpret_cast<const bf16x8*>(VpB2 + (vo0 + 64));                    \
      VN[0][3] = *reinterpret_cast<const bf16x8*>(VpB3 + vo0);                           \
      VN[1][3] = *reinterpret_cast<const bf16x8*>(VpB3 + (vo0 + 64));                    \
      vo0 += 128;                                                                        \
      if ((KT) < 62) { KN = *reinterpret_cast<const bf16x8*>(Kpc + vok); vok += 4096; }  \
      /* QK(KT+1) + exp + packed b64 write P[CUR^1] */                                   \
      _Pragma("unroll") for (int mt = 0; mt < 8; ++mt) {                                 \
        f32x4 s = __builtin_amdgcn_mfma_f32_16x16x32_bf16(KC, qfr[mt], zero, 0, 0, 0);   \
        float p0 = exp2_hw(fminf(s[0], 28.f)), p1 = exp2_hw(fminf(s[1], 28.f));          \
        float p2 = exp2_hw(fminf(s[2], 28.f)), p3 = exp2_hw(fminf(s[3], 28.f));          \
        lsum[mt] += (p0 + p1) + (p2 + p3);                                               \
        *reinterpret_cast<u64*>(pW + (((CUR) ^ 1) * 16384 + mt * 2048)) =                \
            (u64)cvt_pk_bf16(p0, p1) | ((u64)cvt_pk_bf16(p2, p3) << 32);                 \
      }                                                                                  \
    }                                                                                    \
    /* PV(KT) */                                                                         \
    __builtin_amdgcn_s_setprio(1);                                                       \
    _Pragma("unroll") for (int mt = 0; mt < 4; ++mt)                                     \
      _Pragma("unroll") for (int nt = 0; nt < 4; ++nt)                                   \
        acc[mt][nt] =                                                                    \
            __builtin_amdgcn_mfma_f32_16x16x32_bf16(afr0[mt], VC[0][nt], acc[mt][nt], 0, 0, 0); \
    _Pragma("unroll") for (int mt = 0; mt < 4; ++mt)                                     \
      _Pragma("unroll") for (int nt = 0; nt < 4; ++nt)                                   \
        acc[mt][nt] =                                                                    \
            __builtin_amdgcn_mfma_f32_16x16x32_bf16(afr1[mt], VC[1][nt], acc[mt][nt], 0, 0, 0); \
    __builtin_amdgcn_s_setprio(0);                                                       \
    __syncthreads();                                                                     \
  }

  for (int it = 0; it < 32; ++it) {
    ATTN_ITER(2 * it, 0, vfrA, vfrB, kfrA, kfrB)
    ATTN_ITER(2 * it + 1, 1, vfrB, vfrA, kfrB, kfrA)
  }
#undef ATTN_ITER

  // ---- row sums: reduce over l4 groups, publish per-wave strip sums ----
#pragma unroll
  for (int mt = 0; mt < 8; ++mt) {
    lsum[mt] += __shfl_xor(lsum[mt], 16, 64);
    lsum[mt] += __shfl_xor(lsum[mt], 32, 64);
  }
  if (l4 == 0) {
#pragma unroll
    for (int mt = 0; mt < 8; ++mt) lred[w][mt * 16 + l15] = lsum[mt];
  }
  __syncthreads();

  const float g = gamma[0];
  float linv[16];
#pragma unroll
  for (int mt = 0; mt < 4; ++mt)
#pragma unroll
    for (int r = 0; r < 4; ++r) {
      int tok = th * 64 + mt * 16 + l4 * 4 + r;
      linv[mt * 4 + r] = 1.0f / (lred[0][tok] + lred[1][tok] + lred[2][tok] + lred[3][tok]);
    }
  // ---- epilogue: out = gamma * acc / l + x ----
#pragma unroll
  for (int mt = 0; mt < 4; ++mt) {
#pragma unroll
    for (int nt = 0; nt < 4; ++nt) {
      int ch = CHW + nt * 16 + l15;
      size_t idx = ((size_t)(b * 256 + ch)) * 16384 + t0 + th * 64 + mt * 16 + l4 * 4;
      float4 xr = *reinterpret_cast<const float4*>(x + idx);
      float4 o;
      o.x = g * acc[mt][nt][0] * linv[mt * 4 + 0] + xr.x;
      o.y = g * acc[mt][nt][1] * linv[mt * 4 + 1] + xr.y;
      o.z = g * acc[mt][nt][2] * linv[mt * 4 + 2] + xr.z;
      o.w = g * acc[mt][nt][3] * linv[mt * 4 + 3] + xr.w;
      *reinterpret_cast<float4*>(out + idx) = o;
    }
  }
}

// ---------------------------------------------------------------------------
extern "C" void kernel_launch(void* const* d_in, const int* in_sizes, int n_in,
                              void* d_out, int out_size, void* d_ws, size_t ws_size,
                              hipStream_t stream) {
  const float* x = (const float*)d_in[0];
  const float* Wq = (const float*)d_in[1];
  const float* bq = (const float*)d_in[2];
  const float* Wk = (const float*)d_in[3];
  const float* bk = (const float*)d_in[4];
  const float* Wv = (const float*)d_in[5];
  const float* bv = (const float*)d_in[6];
  const float* gamma = (const float*)d_in[7];
  float* out = (float*)d_out;

  char* ws = (char*)d_ws;
  u16* Qb = (u16*)ws;                                // 2 MB  : [2][16384][32]
  u16* Kt = (u16*)(ws + (2u << 20));                 // 512 KB: [2][4096][32]
  u16* Vb = (u16*)(ws + (2u << 20) + (512u << 10));  // 4 MB  : [2][256][4096]

  proj_kernel<<<dim3(768), 256, 0, stream>>>(x, Wq, bq, Wk, bk, Wv, bv, Qb, Kt, Vb);
  attn_kernel<<<dim3(512), 256, 0, stream>>>(Qb, Kt, Vb, x, gamma, out);
}

// Round 10
// 137.533 us; speedup vs baseline: 1.8219x; 1.8219x over previous
//
#include <hip/hip_runtime.h>

typedef unsigned short u16;
typedef unsigned int u32;
typedef unsigned long long u64;
typedef float f32x4 __attribute__((ext_vector_type(4)));
typedef __bf16 bf16x8 __attribute__((ext_vector_type(8)));

// f32 -> bf16 round-to-nearest-even (scalar)
__device__ __forceinline__ u16 f2bf(float f) {
  unsigned u = __float_as_uint(f);
  unsigned r = u + 0x7fffu + ((u >> 16) & 1u);
  return (u16)(r >> 16);
}
// packed f32 pair -> 2x bf16 in one u32 (lo = first arg)
__device__ __forceinline__ u32 cvt_pk_bf16(float lo, float hi) {
  u32 r;
  asm("v_cvt_pk_bf16_f32 %0, %1, %2" : "=v"(r) : "v"(lo), "v"(hi));
  return r;
}
// hardware 2^x
__device__ __forceinline__ float exp2_hw(float x) {
  float r;
  asm("v_exp_f32 %0, %1" : "=v"(r) : "v"(x));
  return r;
}
__device__ __forceinline__ bf16x8 f32x8_to_bf16x8(float4 a, float4 b) {
  union { u32 u[4]; bf16x8 v; } t;
  t.u[0] = cvt_pk_bf16(a.x, a.y);
  t.u[1] = cvt_pk_bf16(a.z, a.w);
  t.u[2] = cvt_pk_bf16(b.x, b.y);
  t.u[3] = cvt_pk_bf16(b.z, b.w);
  return t.v;
}
// async global->LDS, 16B per lane; dest = uniform base + lane*16 (HW rule)
__device__ __forceinline__ void gload_lds16(const void* g, u16* l) {
  __builtin_amdgcn_global_load_lds(
      (const __attribute__((address_space(1))) unsigned int*)g,
      (__attribute__((address_space(3))) unsigned int*)l, 16, 0, 0);
}

// 1/sqrt(32) * log2(e)  — softmax scale folded with exp->exp2 conversion
#define QSCALE 0.25513936f

// ---------------------------------------------------------------------------
// proj_kernel (unchanged, R7-verified): blocks 0..255 -> fused pooled K+V
// path, z-split; blocks 256..767 -> Q path (LDS-staged MFMA).
// Layouts: Qb[b][t][32], Kt[b][s][32], Vb[b][ch][4096].
// ---------------------------------------------------------------------------
__global__ __launch_bounds__(256) void proj_kernel(
    const float* __restrict__ x, const float* __restrict__ Wq, const float* __restrict__ bq,
    const float* __restrict__ Wk, const float* __restrict__ bk, const float* __restrict__ Wv,
    const float* __restrict__ bv, u16* __restrict__ Qb, u16* __restrict__ Kt,
    u16* __restrict__ Vb) {
  __shared__ __align__(16) u16 smem[24576];  // 48KB: xt(32KB)+wq(16KB) | xs(32KB)
  const int tid = threadIdx.x;
  const int lane = tid & 63, w = tid >> 6;
  const int l15 = lane & 15, l4 = lane >> 4;
  const int bi = blockIdx.x;
  const f32x4 zero = {0.f, 0.f, 0.f, 0.f};

  if (bi >= 256) {
    // ================= Q path (verified, LDS-staged) =================
    u16* xt = smem;          // [64 t][256 c] bf16, swizzled
    u16* wq = smem + 16384;  // [32 oc][256 c] bf16, swizzled, pre-scaled
    const int j = bi - 256;
    const int b = j >> 8, tb = j & 255;
    const float* xp = x + (size_t)b * 256 * 16384 + tb * 64;

    for (int i = tid; i < 4096; i += 256) {
      int oc = i >> 7, c0 = (i & 127) * 2;
      float2 f = *reinterpret_cast<const float2*>(Wq + oc * 256 + c0);
      u32 pk = cvt_pk_bf16(f.x * QSCALE, f.y * QSCALE);
      *reinterpret_cast<u32*>((char*)wq + oc * 512 + (((c0 >> 3) ^ (oc & 7)) * 16) +
                              (c0 & 7) * 2) = pk;
    }
#pragma unroll
    for (int rr = 0; rr < 4; ++rr) {
      int c = rr * 64 + (tid >> 2);
      int tch = (tid & 3) * 16;
      const float* src = xp + (size_t)c * 16384 + tch;
#pragma unroll
      for (int u = 0; u < 4; ++u) {
        float4 f = *reinterpret_cast<const float4*>(src + u * 4);
        int t = tch + u * 4;
        *reinterpret_cast<u16*>((char*)xt + (t + 0) * 512 + (((c >> 3) ^ ((t + 0) & 7)) * 16) + (c & 7) * 2) = f2bf(f.x);
        *reinterpret_cast<u16*>((char*)xt + (t + 1) * 512 + (((c >> 3) ^ ((t + 1) & 7)) * 16) + (c & 7) * 2) = f2bf(f.y);
        *reinterpret_cast<u16*>((char*)xt + (t + 2) * 512 + (((c >> 3) ^ ((t + 2) & 7)) * 16) + (c & 7) * 2) = f2bf(f.z);
        *reinterpret_cast<u16*>((char*)xt + (t + 3) * 512 + (((c >> 3) ^ ((t + 3) & 7)) * 16) + (c & 7) * 2) = f2bf(f.w);
      }
    }
    __syncthreads();

    f32x4 acc[2] = {zero, zero};
    const int tl = w * 16 + l15;
#pragma unroll
    for (int k = 0; k < 8; ++k) {
      bf16x8 bf = *reinterpret_cast<const bf16x8*>((char*)xt + tl * 512 +
                                                   (((k * 4 + l4) ^ (tl & 7)) * 16));
#pragma unroll
      for (int m = 0; m < 2; ++m) {
        int oc = m * 16 + l15;
        bf16x8 af = *reinterpret_cast<const bf16x8*>((char*)wq + oc * 512 +
                                                     (((k * 4 + l4) ^ (oc & 7)) * 16));
        acc[m] = __builtin_amdgcn_mfma_f32_16x16x32_bf16(af, bf, acc[m], 0, 0, 0);
      }
    }
    const int t = tb * 64 + tl;
#pragma unroll
    for (int m = 0; m < 2; ++m) {
      int oc0 = m * 16 + l4 * 4;
      u32 p0 = cvt_pk_bf16(acc[m][0] + bq[oc0] * QSCALE, acc[m][1] + bq[oc0 + 1] * QSCALE);
      u32 p1 = cvt_pk_bf16(acc[m][2] + bq[oc0 + 2] * QSCALE, acc[m][3] + bq[oc0 + 3] * QSCALE);
      u16* dst = Qb + ((size_t)b * 16384 + t) * 32 + oc0;
      *reinterpret_cast<u32*>(dst) = p0;
      *reinterpret_cast<u32*>(dst + 2) = p1;
    }
  } else {
    // ================= fused K+V path, z-split =================
    u16* xs = smem;  // pooled [64 s][256 c] bf16, swizzled
    const int b = bi >> 7, r2 = bi & 127;
    const int sy = r2 >> 1, z = r2 & 1;
    const int mb = z * 8;
    const float* xb = x + (size_t)b * 256 * 16384;

#pragma unroll
    for (int rr = 0; rr < 4; ++rr) {
      int c = rr * 64 + (tid >> 2);
      int f4base = (tid & 3) * 8;
      const float* r0 = xb + (size_t)c * 16384 + (size_t)sy * 256;
#pragma unroll
      for (int u = 0; u < 8; ++u) {
        int jj = f4base + u;
        float4 a = *reinterpret_cast<const float4*>(r0 + jj * 4);
        float4 d = *reinterpret_cast<const float4*>(r0 + 128 + jj * 4);
        float p0 = (a.x + a.y + d.x + d.y) * 0.25f;
        float p1 = (a.z + a.w + d.z + d.w) * 0.25f;
        int s0 = jj * 2;
        *reinterpret_cast<u16*>((char*)xs + (s0 + 0) * 512 + (((c >> 3) ^ ((s0 + 0) & 7)) * 16) + (c & 7) * 2) = f2bf(p0);
        *reinterpret_cast<u16*>((char*)xs + (s0 + 1) * 512 + (((c >> 3) ^ ((s0 + 1) & 7)) * 16) + (c & 7) * 2) = f2bf(p1);
      }
    }
    __syncthreads();

    f32x4 acc[10];
#pragma unroll
    for (int m = 0; m < 10; ++m) acc[m] = zero;
    const int sl = w * 16 + l15;
#pragma unroll
    for (int k = 0; k < 8; ++k) {
      bf16x8 bf = *reinterpret_cast<const bf16x8*>((char*)xs + sl * 512 +
                                                   (((k * 4 + l4) ^ (sl & 7)) * 16));
      if (z == 0) {
#pragma unroll
        for (int m = 0; m < 2; ++m) {
          const float* wr = Wk + (size_t)(m * 16 + l15) * 256 + k * 32 + l4 * 8;
          float4 fa = *reinterpret_cast<const float4*>(wr);
          float4 fb = *reinterpret_cast<const float4*>(wr + 4);
          acc[m] = __builtin_amdgcn_mfma_f32_16x16x32_bf16(f32x8_to_bf16x8(fa, fb), bf, acc[m], 0, 0, 0);
        }
      }
#pragma unroll
      for (int mm = 0; mm < 8; ++mm) {
        const float* wr = Wv + (size_t)((mb + mm) * 16 + l15) * 256 + k * 32 + l4 * 8;
        float4 fa = *reinterpret_cast<const float4*>(wr);
        float4 fb = *reinterpret_cast<const float4*>(wr + 4);
        acc[2 + mm] = __builtin_amdgcn_mfma_f32_16x16x32_bf16(f32x8_to_bf16x8(fa, fb), bf, acc[2 + mm], 0, 0, 0);
      }
    }
    if (z == 0) {
#pragma unroll
      for (int m = 0; m < 2; ++m) {
        int oc0 = m * 16 + l4 * 4;
        u32 p0 = cvt_pk_bf16(acc[m][0] + bk[oc0], acc[m][1] + bk[oc0 + 1]);
        u32 p1 = cvt_pk_bf16(acc[m][2] + bk[oc0 + 2], acc[m][3] + bk[oc0 + 3]);
        u16* dst = Kt + ((size_t)b * 4096 + sy * 64 + sl) * 32 + oc0;
        *reinterpret_cast<u32*>(dst) = p0;
        *reinterpret_cast<u32*>(dst + 2) = p1;
      }
    }
#pragma unroll
    for (int mm = 0; mm < 8; ++mm) {
#pragma unroll
      for (int r = 0; r < 4; ++r) {
        int oc = (mb + mm) * 16 + l4 * 4 + r;
        Vb[((size_t)b * 256 + oc) * 4096 + sy * 64 + sl] = f2bf(acc[2 + mm][r] + bv[oc]);
      }
    }
  }
}

// ---------------------------------------------------------------------------
// attn v10: V double-buffered in LDS via global_load_lds (zero VGPR staging,
// issued at iteration TOP -> pre-barrier vmcnt(0) drain is pre-paid).
// Source-pre-swizzled staging: lane L of instr i loads key-chunk
// kc=(L&7)^(L>>3) of ch=(w*4+i)*8+(L>>3); linear LDS dest then equals the
// XOR-swizzled layout; reads at ((ks*4+l4)^l7)*16 are conflict-free.
// PV V-frags are transient ds_reads in 2 ks-halves (caps VGPR ~195, no spill
// — R9's lesson). p_lds/P path, addressing, setprio as R9 (numerics-verified).
// LDS: p_lds 32KB + v_lds 32KB = 64KB; lred aliased into dead v_lds.
// ---------------------------------------------------------------------------
__global__ __launch_bounds__(256, 2) void attn_kernel(
    const u16* __restrict__ Qb, const u16* __restrict__ Kt, const u16* __restrict__ Vb,
    const float* __restrict__ x, const float* __restrict__ gamma, float* __restrict__ out) {
  __shared__ __align__(16) u16 p_lds[2][128 * 64];  // 32KB dbuf P
  __shared__ __align__(16) u16 v_lds[2][128 * 64];  // 32KB dbuf V tiles

  const int tid = threadIdx.x;
  const int lane = tid & 63, w = tid >> 6;
  const int l15 = lane & 15, l4 = lane >> 4, l7 = l15 & 7;
  const int raw = blockIdx.x;               // 0..511
  const int xcd = raw & 7, loc = raw >> 3;  // loc 0..63
  const int b = xcd >> 2;
  const int H = loc & 1;
  const int tt = (xcd & 3) * 32 + (loc >> 1);
  const int t0 = tt * 128;
  const int th = w >> 1, chh = w & 1;
  const int CHW = H * 128 + chh * 64;

  const u16* Qp = Qb + (size_t)(b * 16384 + t0) * 32;
  const u16* Kp = Kt + (size_t)b * 4096 * 32;
  const char* Kpc = (const char*)Kp;
  const char* Vpc = (const char*)(Vb + (size_t)b * 256 * 4096);

  // Q fragments (loop-invariant)
  bf16x8 qfr[8];
#pragma unroll
  for (int mt = 0; mt < 8; ++mt)
    qfr[mt] = *reinterpret_cast<const bf16x8*>(Qp + (size_t)(mt * 16 + l15) * 32 + l4 * 8);

  const int key = w * 16 + l15;
  const int pw_chunk = w * 2 + (l4 >> 1), pw_off = (l4 & 1) * 8;

  // ---- loop-invariant lane bases (LDS); valid since tok&7 == l7 ----
  char* pA0 = (char*)p_lds + (th * 64 + l15) * 128 + ((l4 ^ l7) * 16);
  char* pA1 = (char*)p_lds + (th * 64 + l15) * 128 + (((4 + l4) ^ l7) * 16);
  char* pW = (char*)p_lds + l15 * 128 + ((pw_chunk ^ l7) * 16) + pw_off;
  // V read lane bases (swizzled): block = chh*8 + nt*2 + (l15>>3)
  char* pV0 = (char*)v_lds + chh * 8192 + (l15 >> 3) * 1024 + l7 * 128 + ((l4 ^ l7) * 16);
  char* pV1 = (char*)v_lds + chh * 8192 + (l15 >> 3) * 1024 + l7 * 128 + (((4 ^ l4) ^ l7) * 16);

  // ---- staging: per-lane pre-swizzled global source offset ----
  const int sch = lane >> 3;           // sub-channel within 8-ch group
  const int skc = (lane & 7) ^ sch;    // source key-chunk (inverse of read swz)
  u32 vstg = (u32)(H * 128 + w * 32 + sch) * 8192 + (u32)skc * 16 + 128;  // kt=1
  u32 vok = 2 * 4096 + key * 64 + l4 * 16;  // K(kt=2) running offset

  f32x4 acc[4][4] = {};
  float lsum[8] = {};
  const f32x4 zero = {0.f, 0.f, 0.f, 0.f};

  // ---- prologue: stage V(0) -> vbuf0; QK(0) -> p_lds[0]; kfr = K(1) ----
#pragma unroll
  for (int i = 0; i < 4; ++i)
    gload_lds16(Vpc + (vstg - 128) + i * 65536, (u16*)v_lds + (w * 4 + i) * 512);
  {
    bf16x8 k0 = *reinterpret_cast<const bf16x8*>(Kp + (size_t)key * 32 + l4 * 8);
#pragma unroll
    for (int mt = 0; mt < 8; ++mt) {
      f32x4 s = __builtin_amdgcn_mfma_f32_16x16x32_bf16(k0, qfr[mt], zero, 0, 0, 0);
      float p0 = exp2_hw(fminf(s[0], 28.f)), p1 = exp2_hw(fminf(s[1], 28.f));
      float p2 = exp2_hw(fminf(s[2], 28.f)), p3 = exp2_hw(fminf(s[3], 28.f));
      lsum[mt] += (p0 + p1) + (p2 + p3);
      *reinterpret_cast<u64*>(pW + mt * 2048) =
          (u64)cvt_pk_bf16(p0, p1) | ((u64)cvt_pk_bf16(p2, p3) << 32);
    }
  }
  bf16x8 kfr = *reinterpret_cast<const bf16x8*>(Kpc + (4096 + key * 64 + l4 * 16));
  __syncthreads();  // drains the V(0) DMA too

#define ATTN_ITER(KT, CUR)                                                               \
  {                                                                                      \
    if ((KT) < 63) {                                                                     \
      /* stage V(KT+1) -> vbuf[CUR^1]: 4 DMA instrs, no VGPR, full iter to land */       \
      _Pragma("unroll") for (int i = 0; i < 4; ++i)                                      \
          gload_lds16(Vpc + vstg + i * 65536,                                            \
                      (u16*)v_lds + ((CUR) ^ 1) * 8192 + (w * 4 + i) * 512);             \
      vstg += 128;                                                                       \
    }                                                                                    \
    /* ks=0 operand reads (latency hidden under QK/exp below) */                         \
    bf16x8 afr0[4], vfr0[4];                                                             \
    _Pragma("unroll") for (int mt = 0; mt < 4; ++mt)                                     \
        afr0[mt] = *reinterpret_cast<const bf16x8*>(pA0 + ((CUR)*16384 + mt * 2048));    \
    _Pragma("unroll") for (int nt = 0; nt < 4; ++nt)                                     \
        vfr0[nt] = *reinterpret_cast<const bf16x8*>(pV0 + ((CUR)*16384 + nt * 2048));    \
    if ((KT) < 63) {                                                                     \
      /* QK(KT+1) + exp + packed b64 write P[CUR^1] */                                   \
      _Pragma("unroll") for (int mt = 0; mt < 8; ++mt) {                                 \
        f32x4 s = __builtin_amdgcn_mfma_f32_16x16x32_bf16(kfr, qfr[mt], zero, 0, 0, 0);  \
        float p0 = exp2_hw(fminf(s[0], 28.f)), p1 = exp2_hw(fminf(s[1], 28.f));          \
        float p2 = exp2_hw(fminf(s[2], 28.f)), p3 = exp2_hw(fminf(s[3], 28.f));          \
        lsum[mt] += (p0 + p1) + (p2 + p3);                                               \
        *reinterpret_cast<u64*>(pW + (((CUR) ^ 1) * 16384 + mt * 2048)) =                \
            (u64)cvt_pk_bf16(p0, p1) | ((u64)cvt_pk_bf16(p2, p3) << 32);                 \
      }                                                                                  \
      if ((KT) < 62) {                                                                   \
        kfr = *reinterpret_cast<const bf16x8*>(Kpc + vok);                               \
        vok += 4096;                                                                     \
      }                                                                                  \
    }                                                                                    \
    /* PV(KT) in two ks-halves; V-frags transient from LDS */                            \
    __builtin_amdgcn_s_setprio(1);                                                       \
    _Pragma("unroll") for (int mt = 0; mt < 4; ++mt)                                     \
      _Pragma("unroll") for (int nt = 0; nt < 4; ++nt)                                   \
        acc[mt][nt] =                                                                    \
            __builtin_amdgcn_mfma_f32_16x16x32_bf16(afr0[mt], vfr0[nt], acc[mt][nt], 0, 0, 0); \
    bf16x8 afr1[4], vfr1[4];                                                             \
    _Pragma("unroll") for (int mt = 0; mt < 4; ++mt)                                     \
        afr1[mt] = *reinterpret_cast<const bf16x8*>(pA1 + ((CUR)*16384 + mt * 2048));    \
    _Pragma("unroll") for (int nt = 0; nt < 4; ++nt)                                     \
        vfr1[nt] = *reinterpret_cast<const bf16x8*>(pV1 + ((CUR)*16384 + nt * 2048));    \
    _Pragma("unroll") for (int mt = 0; mt < 4; ++mt)                                     \
      _Pragma("unroll") for (int nt = 0; nt < 4; ++nt)                                   \
        acc[mt][nt] =                                                                    \
            __builtin_amdgcn_mfma_f32_16x16x32_bf16(afr1[mt], vfr1[nt], acc[mt][nt], 0, 0, 0); \
    __builtin_amdgcn_s_setprio(0);                                                       \
    __syncthreads();                                                                     \
  }

  for (int it = 0; it < 32; ++it) {
    ATTN_ITER(2 * it, 0)
    ATTN_ITER(2 * it + 1, 1)
  }
#undef ATTN_ITER

  // ---- row sums: reduce over l4 groups; lred aliased into dead v_lds ----
  float* lred = (float*)v_lds;  // [4][128]; safe: loop ended with barrier
#pragma unroll
  for (int mt = 0; mt < 8; ++mt) {
    lsum[mt] += __shfl_xor(lsum[mt], 16, 64);
    lsum[mt] += __shfl_xor(lsum[mt], 32, 64);
  }
  if (l4 == 0) {
#pragma unroll
    for (int mt = 0; mt < 8; ++mt) lred[w * 128 + mt * 16 + l15] = lsum[mt];
  }
  __syncthreads();

  const float g = gamma[0];
  float linv[16];
#pragma unroll
  for (int mt = 0; mt < 4; ++mt)
#pragma unroll
    for (int r = 0; r < 4; ++r) {
      int tok = th * 64 + mt * 16 + l4 * 4 + r;
      linv[mt * 4 + r] =
          1.0f / (lred[tok] + lred[128 + tok] + lred[256 + tok] + lred[384 + tok]);
    }
  // ---- epilogue: out = gamma * acc / l + x ----
#pragma unroll
  for (int mt = 0; mt < 4; ++mt) {
#pragma unroll
    for (int nt = 0; nt < 4; ++nt) {
      int ch = CHW + nt * 16 + l15;
      size_t idx = ((size_t)(b * 256 + ch)) * 16384 + t0 + th * 64 + mt * 16 + l4 * 4;
      float4 xr = *reinterpret_cast<const float4*>(x + idx);
      float4 o;
      o.x = g * acc[mt][nt][0] * linv[mt * 4 + 0] + xr.x;
      o.y = g * acc[mt][nt][1] * linv[mt * 4 + 1] + xr.y;
      o.z = g * acc[mt][nt][2] * linv[mt * 4 + 2] + xr.z;
      o.w = g * acc[mt][nt][3] * linv[mt * 4 + 3] + xr.w;
      *reinterpret_cast<float4*>(out + idx) = o;
    }
  }
}

// ---------------------------------------------------------------------------
extern "C" void kernel_launch(void* const* d_in, const int* in_sizes, int n_in,
                              void* d_out, int out_size, void* d_ws, size_t ws_size,
                              hipStream_t stream) {
  const float* x = (const float*)d_in[0];
  const float* Wq = (const float*)d_in[1];
  const float* bq = (const float*)d_in[2];
  const float* Wk = (const float*)d_in[3];
  const float* bk = (const float*)d_in[4];
  const float* Wv = (const float*)d_in[5];
  const float* bv = (const float*)d_in[6];
  const float* gamma = (const float*)d_in[7];
  float* out = (float*)d_out;

  char* ws = (char*)d_ws;
  u16* Qb = (u16*)ws;                                // 2 MB  : [2][16384][32]
  u16* Kt = (u16*)(ws + (2u << 20));                 // 512 KB: [2][4096][32]
  u16* Vb = (u16*)(ws + (2u << 20) + (512u << 10));  // 4 MB  : [2][256][4096]

  proj_kernel<<<dim3(768), 256, 0, stream>>>(x, Wq, bq, Wk, bk, Wv, bv, Qb, Kt, Vb);
  attn_kernel<<<dim3(512), 256, 0, stream>>>(Qb, Kt, Vb, x, gamma, out);
}

// Round 11
// 133.456 us; speedup vs baseline: 1.8776x; 1.0305x over previous
//
#include <hip/hip_runtime.h>

typedef unsigned short u16;
typedef unsigned int u32;
typedef unsigned long long u64;
typedef float f32x4 __attribute__((ext_vector_type(4)));
typedef __bf16 bf16x8 __attribute__((ext_vector_type(8)));

// f32 -> bf16 round-to-nearest-even (scalar)
__device__ __forceinline__ u16 f2bf(float f) {
  unsigned u = __float_as_uint(f);
  unsigned r = u + 0x7fffu + ((u >> 16) & 1u);
  return (u16)(r >> 16);
}
// packed f32 pair -> 2x bf16 in one u32 (lo = first arg)
__device__ __forceinline__ u32 cvt_pk_bf16(float lo, float hi) {
  u32 r;
  asm("v_cvt_pk_bf16_f32 %0, %1, %2" : "=v"(r) : "v"(lo), "v"(hi));
  return r;
}
// hardware 2^x
__device__ __forceinline__ float exp2_hw(float x) {
  float r;
  asm("v_exp_f32 %0, %1" : "=v"(r) : "v"(x));
  return r;
}
__device__ __forceinline__ bf16x8 f32x8_to_bf16x8(float4 a, float4 b) {
  union { u32 u[4]; bf16x8 v; } t;
  t.u[0] = cvt_pk_bf16(a.x, a.y);
  t.u[1] = cvt_pk_bf16(a.z, a.w);
  t.u[2] = cvt_pk_bf16(b.x, b.y);
  t.u[3] = cvt_pk_bf16(b.z, b.w);
  return t.v;
}
// async global->LDS, 16B per lane; dest = uniform base + lane*16 (HW rule)
__device__ __forceinline__ void gload_lds16(const void* g, u16* l) {
  __builtin_amdgcn_global_load_lds(
      (const __attribute__((address_space(1))) unsigned int*)g,
      (__attribute__((address_space(3))) unsigned int*)l, 16, 0, 0);
}

// 1/sqrt(32) * log2(e)  — softmax scale folded with exp->exp2 conversion
#define QSCALE 0.25513936f

// ---------------------------------------------------------------------------
// proj_kernel (unchanged, R7-verified): blocks 0..255 -> fused pooled K+V
// path, z-split; blocks 256..767 -> Q path (LDS-staged MFMA).
// Layouts: Qb[b][t][32], Kt[b][s][32], Vb[b][ch][4096].
// ---------------------------------------------------------------------------
__global__ __launch_bounds__(256) void proj_kernel(
    const float* __restrict__ x, const float* __restrict__ Wq, const float* __restrict__ bq,
    const float* __restrict__ Wk, const float* __restrict__ bk, const float* __restrict__ Wv,
    const float* __restrict__ bv, u16* __restrict__ Qb, u16* __restrict__ Kt,
    u16* __restrict__ Vb) {
  __shared__ __align__(16) u16 smem[24576];  // 48KB: xt(32KB)+wq(16KB) | xs(32KB)
  const int tid = threadIdx.x;
  const int lane = tid & 63, w = tid >> 6;
  const int l15 = lane & 15, l4 = lane >> 4;
  const int bi = blockIdx.x;
  const f32x4 zero = {0.f, 0.f, 0.f, 0.f};

  if (bi >= 256) {
    // ================= Q path (verified, LDS-staged) =================
    u16* xt = smem;          // [64 t][256 c] bf16, swizzled
    u16* wq = smem + 16384;  // [32 oc][256 c] bf16, swizzled, pre-scaled
    const int j = bi - 256;
    const int b = j >> 8, tb = j & 255;
    const float* xp = x + (size_t)b * 256 * 16384 + tb * 64;

    for (int i = tid; i < 4096; i += 256) {
      int oc = i >> 7, c0 = (i & 127) * 2;
      float2 f = *reinterpret_cast<const float2*>(Wq + oc * 256 + c0);
      u32 pk = cvt_pk_bf16(f.x * QSCALE, f.y * QSCALE);
      *reinterpret_cast<u32*>((char*)wq + oc * 512 + (((c0 >> 3) ^ (oc & 7)) * 16) +
                              (c0 & 7) * 2) = pk;
    }
#pragma unroll
    for (int rr = 0; rr < 4; ++rr) {
      int c = rr * 64 + (tid >> 2);
      int tch = (tid & 3) * 16;
      const float* src = xp + (size_t)c * 16384 + tch;
#pragma unroll
      for (int u = 0; u < 4; ++u) {
        float4 f = *reinterpret_cast<const float4*>(src + u * 4);
        int t = tch + u * 4;
        *reinterpret_cast<u16*>((char*)xt + (t + 0) * 512 + (((c >> 3) ^ ((t + 0) & 7)) * 16) + (c & 7) * 2) = f2bf(f.x);
        *reinterpret_cast<u16*>((char*)xt + (t + 1) * 512 + (((c >> 3) ^ ((t + 1) & 7)) * 16) + (c & 7) * 2) = f2bf(f.y);
        *reinterpret_cast<u16*>((char*)xt + (t + 2) * 512 + (((c >> 3) ^ ((t + 2) & 7)) * 16) + (c & 7) * 2) = f2bf(f.z);
        *reinterpret_cast<u16*>((char*)xt + (t + 3) * 512 + (((c >> 3) ^ ((t + 3) & 7)) * 16) + (c & 7) * 2) = f2bf(f.w);
      }
    }
    __syncthreads();

    f32x4 acc[2] = {zero, zero};
    const int tl = w * 16 + l15;
#pragma unroll
    for (int k = 0; k < 8; ++k) {
      bf16x8 bf = *reinterpret_cast<const bf16x8*>((char*)xt + tl * 512 +
                                                   (((k * 4 + l4) ^ (tl & 7)) * 16));
#pragma unroll
      for (int m = 0; m < 2; ++m) {
        int oc = m * 16 + l15;
        bf16x8 af = *reinterpret_cast<const bf16x8*>((char*)wq + oc * 512 +
                                                     (((k * 4 + l4) ^ (oc & 7)) * 16));
        acc[m] = __builtin_amdgcn_mfma_f32_16x16x32_bf16(af, bf, acc[m], 0, 0, 0);
      }
    }
    const int t = tb * 64 + tl;
#pragma unroll
    for (int m = 0; m < 2; ++m) {
      int oc0 = m * 16 + l4 * 4;
      u32 p0 = cvt_pk_bf16(acc[m][0] + bq[oc0] * QSCALE, acc[m][1] + bq[oc0 + 1] * QSCALE);
      u32 p1 = cvt_pk_bf16(acc[m][2] + bq[oc0 + 2] * QSCALE, acc[m][3] + bq[oc0 + 3] * QSCALE);
      u16* dst = Qb + ((size_t)b * 16384 + t) * 32 + oc0;
      *reinterpret_cast<u32*>(dst) = p0;
      *reinterpret_cast<u32*>(dst + 2) = p1;
    }
  } else {
    // ================= fused K+V path, z-split =================
    u16* xs = smem;  // pooled [64 s][256 c] bf16, swizzled
    const int b = bi >> 7, r2 = bi & 127;
    const int sy = r2 >> 1, z = r2 & 1;
    const int mb = z * 8;
    const float* xb = x + (size_t)b * 256 * 16384;

#pragma unroll
    for (int rr = 0; rr < 4; ++rr) {
      int c = rr * 64 + (tid >> 2);
      int f4base = (tid & 3) * 8;
      const float* r0 = xb + (size_t)c * 16384 + (size_t)sy * 256;
#pragma unroll
      for (int u = 0; u < 8; ++u) {
        int jj = f4base + u;
        float4 a = *reinterpret_cast<const float4*>(r0 + jj * 4);
        float4 d = *reinterpret_cast<const float4*>(r0 + 128 + jj * 4);
        float p0 = (a.x + a.y + d.x + d.y) * 0.25f;
        float p1 = (a.z + a.w + d.z + d.w) * 0.25f;
        int s0 = jj * 2;
        *reinterpret_cast<u16*>((char*)xs + (s0 + 0) * 512 + (((c >> 3) ^ ((s0 + 0) & 7)) * 16) + (c & 7) * 2) = f2bf(p0);
        *reinterpret_cast<u16*>((char*)xs + (s0 + 1) * 512 + (((c >> 3) ^ ((s0 + 1) & 7)) * 16) + (c & 7) * 2) = f2bf(p1);
      }
    }
    __syncthreads();

    f32x4 acc[10];
#pragma unroll
    for (int m = 0; m < 10; ++m) acc[m] = zero;
    const int sl = w * 16 + l15;
#pragma unroll
    for (int k = 0; k < 8; ++k) {
      bf16x8 bf = *reinterpret_cast<const bf16x8*>((char*)xs + sl * 512 +
                                                   (((k * 4 + l4) ^ (sl & 7)) * 16));
      if (z == 0) {
#pragma unroll
        for (int m = 0; m < 2; ++m) {
          const float* wr = Wk + (size_t)(m * 16 + l15) * 256 + k * 32 + l4 * 8;
          float4 fa = *reinterpret_cast<const float4*>(wr);
          float4 fb = *reinterpret_cast<const float4*>(wr + 4);
          acc[m] = __builtin_amdgcn_mfma_f32_16x16x32_bf16(f32x8_to_bf16x8(fa, fb), bf, acc[m], 0, 0, 0);
        }
      }
#pragma unroll
      for (int mm = 0; mm < 8; ++mm) {
        const float* wr = Wv + (size_t)((mb + mm) * 16 + l15) * 256 + k * 32 + l4 * 8;
        float4 fa = *reinterpret_cast<const float4*>(wr);
        float4 fb = *reinterpret_cast<const float4*>(wr + 4);
        acc[2 + mm] = __builtin_amdgcn_mfma_f32_16x16x32_bf16(f32x8_to_bf16x8(fa, fb), bf, acc[2 + mm], 0, 0, 0);
      }
    }
    if (z == 0) {
#pragma unroll
      for (int m = 0; m < 2; ++m) {
        int oc0 = m * 16 + l4 * 4;
        u32 p0 = cvt_pk_bf16(acc[m][0] + bk[oc0], acc[m][1] + bk[oc0 + 1]);
        u32 p1 = cvt_pk_bf16(acc[m][2] + bk[oc0 + 2], acc[m][3] + bk[oc0 + 3]);
        u16* dst = Kt + ((size_t)b * 4096 + sy * 64 + sl) * 32 + oc0;
        *reinterpret_cast<u32*>(dst) = p0;
        *reinterpret_cast<u32*>(dst + 2) = p1;
      }
    }
#pragma unroll
    for (int mm = 0; mm < 8; ++mm) {
#pragma unroll
      for (int r = 0; r < 4; ++r) {
        int oc = (mb + mm) * 16 + l4 * 4 + r;
        Vb[((size_t)b * 256 + oc) * 4096 + sy * 64 + sl] = f2bf(acc[2 + mm][r] + bv[oc]);
      }
    }
  }
}

// ---------------------------------------------------------------------------
// attn v11: 512-thread block = 64 tok x FULL 256 ch (no QK duplication),
// 8 waves: QK role (kw=w&3 key-strip, thf=w>>2 tok-half), PV role (same
// tok-half, chq=w&3 ch-quad). 512 blocks -> 2 blocks/CU = 16 waves/CU =
// 4 waves/SIMD. LDS 48KB: p_lds dbuf 16KB + v_lds single 32KB.
// Two barriers/iter: A = {K(kt+2) reg-load issue, PV(kt) reads+MFMA,
// QK(kt+1) MFMA+exp in regs}; B = {DMA V(kt+1), write P(kt+1)}.
// All addressing: lane-base regs + immediates (tok&7 == l7 identity).
// ---------------------------------------------------------------------------
__global__ __launch_bounds__(512, 4) void attn_kernel(
    const u16* __restrict__ Qb, const u16* __restrict__ Kt, const u16* __restrict__ Vb,
    const float* __restrict__ x, const float* __restrict__ gamma, float* __restrict__ out) {
  __shared__ __align__(16) u16 p_lds[2][64 * 64];  // 16KB dbuf P [tok][key swz]
  __shared__ __align__(16) u16 v_lds[256 * 64];    // 32KB single V [ch][key swz]

  const int tid = threadIdx.x;
  const int lane = tid & 63, w = tid >> 6;
  const int l15 = lane & 15, l4 = lane >> 4, l7 = l15 & 7;
  const int raw = blockIdx.x;               // 0..511
  const int xcd = raw & 7, loc = raw >> 3;  // loc 0..63
  const int b = xcd >> 2;
  const int tt = (xcd & 3) * 64 + loc;      // tok-tile 0..255
  const int t0 = tt * 64;
  const int kw = w & 3, thf = w >> 2;       // QK role
  const int chq = w & 3;                    // PV ch-quad (tok-half = thf)

  const u16* Qp = Qb + (size_t)(b * 16384 + t0) * 32;
  const u16* Kp = Kt + (size_t)b * 4096 * 32;
  const char* Kpc = (const char*)Kp;
  const char* Vpc = (const char*)(Vb + (size_t)b * 256 * 4096);

  // Q fragments (loop-invariant): B-operand col = tok = thf*32 + mt*16 + l15
  bf16x8 qfr[2];
#pragma unroll
  for (int mt = 0; mt < 2; ++mt)
    qfr[mt] = *reinterpret_cast<const bf16x8*>(Qp + (size_t)(thf * 32 + mt * 16 + l15) * 32 + l4 * 8);

  const int key = kw * 16 + l15;  // QK A-operand row
  const int pw_chunk = kw * 2 + (l4 >> 1), pw_off = (l4 & 1) * 8;

  // ---- loop-invariant lane bases (valid: tok&7 == l7, ch&7 == l7) ----
  char* pA0 = (char*)p_lds + (thf * 32 + l15) * 128 + ((l4 ^ l7) * 16);
  char* pA1 = (char*)p_lds + (thf * 32 + l15) * 128 + (((4 ^ l4) ^ l7) * 16);
  char* pW = (char*)p_lds + (thf * 32 + l15) * 128 + ((pw_chunk ^ l7) * 16) + pw_off;
  char* pV0 = (char*)v_lds + (chq * 64 + l15) * 128 + ((l4 ^ l7) * 16);
  char* pV1 = (char*)v_lds + (chq * 64 + l15) * 128 + (((4 ^ l4) ^ l7) * 16);

  // ---- staging: per-lane pre-swizzled source (linear dest == swz layout) ----
  const int sch = lane >> 3;         // sub-channel in 8-ch group
  const int skc = (lane & 7) ^ sch;  // source key-chunk
  const u32 vstg0 = (u32)(w * 32 + sch) * 8192 + (u32)skc * 16;
  u32 vstg = vstg0 + 128;                       // V(kt=1)
  u32 vok = 2 * 4096 + (u32)key * 64 + l4 * 16; // K(kt=2)

  f32x4 acc[2][4] = {};  // [tok mt][ch nt] 32tok x 64ch
  float lsum[2] = {};
  const f32x4 zero = {0.f, 0.f, 0.f, 0.f};

  // ---- prologue: DMA V(0); QK(0) -> p_lds[0]; kfr = K(1) ----
#pragma unroll
  for (int i = 0; i < 4; ++i)
    gload_lds16(Vpc + vstg0 + i * 65536, (u16*)v_lds + (w * 4 + i) * 512);
  {
    bf16x8 k0 = *reinterpret_cast<const bf16x8*>(Kpc + (size_t)key * 64 + l4 * 16);
#pragma unroll
    for (int mt = 0; mt < 2; ++mt) {
      f32x4 s = __builtin_amdgcn_mfma_f32_16x16x32_bf16(k0, qfr[mt], zero, 0, 0, 0);
      float p0 = exp2_hw(fminf(s[0], 28.f)), p1 = exp2_hw(fminf(s[1], 28.f));
      float p2 = exp2_hw(fminf(s[2], 28.f)), p3 = exp2_hw(fminf(s[3], 28.f));
      lsum[mt] += (p0 + p1) + (p2 + p3);
      *reinterpret_cast<u64*>(pW + mt * 2048) =
          (u64)cvt_pk_bf16(p0, p1) | ((u64)cvt_pk_bf16(p2, p3) << 32);
    }
  }
  bf16x8 kfrA = *reinterpret_cast<const bf16x8*>(Kpc + (4096 + (size_t)key * 64 + l4 * 16));
  bf16x8 kfrB;
  __syncthreads();  // drains V(0) DMA too

#define ATTN_ITER(KT, CUR, KC, KN)                                                        \
  {                                                                                       \
    /* phase A: K(KT+2) reg-load in flight across both barriers */                        \
    if ((KT) < 62) { KN = *reinterpret_cast<const bf16x8*>(Kpc + vok); vok += 4096; }     \
    /* PV ks=0 operand reads (latency under QK below) */                                  \
    bf16x8 afr0[2], vfr0[4];                                                              \
    _Pragma("unroll") for (int mt = 0; mt < 2; ++mt)                                      \
        afr0[mt] = *reinterpret_cast<const bf16x8*>(pA0 + ((CUR)*8192 + mt * 2048));      \
    _Pragma("unroll") for (int nt = 0; nt < 4; ++nt)                                      \
        vfr0[nt] = *reinterpret_cast<const bf16x8*>(pV0 + nt * 2048);                     \
    /* QK(KT+1) + exp -> regs (write deferred to phase B) */                              \
    u64 pk0 = 0, pk1 = 0;                                                                 \
    if ((KT) < 63) {                                                                      \
      f32x4 s0 = __builtin_amdgcn_mfma_f32_16x16x32_bf16(KC, qfr[0], zero, 0, 0, 0);      \
      f32x4 s1 = __builtin_amdgcn_mfma_f32_16x16x32_bf16(KC, qfr[1], zero, 0, 0, 0);      \
      float a0 = exp2_hw(fminf(s0[0], 28.f)), a1 = exp2_hw(fminf(s0[1], 28.f));           \
      float a2 = exp2_hw(fminf(s0[2], 28.f)), a3 = exp2_hw(fminf(s0[3], 28.f));           \
      float b0 = exp2_hw(fminf(s1[0], 28.f)), b1 = exp2_hw(fminf(s1[1], 28.f));           \
      float b2 = exp2_hw(fminf(s1[2], 28.f)), b3 = exp2_hw(fminf(s1[3], 28.f));           \
      lsum[0] += (a0 + a1) + (a2 + a3);                                                   \
      lsum[1] += (b0 + b1) + (b2 + b3);                                                   \
      pk0 = (u64)cvt_pk_bf16(a0, a1) | ((u64)cvt_pk_bf16(a2, a3) << 32);                  \
      pk1 = (u64)cvt_pk_bf16(b0, b1) | ((u64)cvt_pk_bf16(b2, b3) << 32);                  \
    }                                                                                     \
    /* PV(KT): two ks-halves */                                                           \
    __builtin_amdgcn_s_setprio(1);                                                        \
    _Pragma("unroll") for (int mt = 0; mt < 2; ++mt)                                      \
      _Pragma("unroll") for (int nt = 0; nt < 4; ++nt)                                    \
        acc[mt][nt] =                                                                     \
            __builtin_amdgcn_mfma_f32_16x16x32_bf16(afr0[mt], vfr0[nt], acc[mt][nt], 0, 0, 0); \
    bf16x8 afr1[2], vfr1[4];                                                              \
    _Pragma("unroll") for (int mt = 0; mt < 2; ++mt)                                      \
        afr1[mt] = *reinterpret_cast<const bf16x8*>(pA1 + ((CUR)*8192 + mt * 2048));      \
    _Pragma("unroll") for (int nt = 0; nt < 4; ++nt)                                      \
        vfr1[nt] = *reinterpret_cast<const bf16x8*>(pV1 + nt * 2048);                     \
    _Pragma("unroll") for (int mt = 0; mt < 2; ++mt)                                      \
      _Pragma("unroll") for (int nt = 0; nt < 4; ++nt)                                    \
        acc[mt][nt] =                                                                     \
            __builtin_amdgcn_mfma_f32_16x16x32_bf16(afr1[mt], vfr1[nt], acc[mt][nt], 0, 0, 0); \
    __builtin_amdgcn_s_setprio(0);                                                        \
    __syncthreads(); /* barrier A: all v_lds / p_lds[CUR] reads done */                   \
    /* phase B: DMA V(KT+1) into v_lds; write P(KT+1) into p_lds[CUR^1] */                \
    if ((KT) < 63) {                                                                      \
      _Pragma("unroll") for (int i = 0; i < 4; ++i)                                       \
          gload_lds16(Vpc + vstg + i * 65536, (u16*)v_lds + (w * 4 + i) * 512);           \
      vstg += 128;                                                                        \
      *reinterpret_cast<u64*>(pW + (((CUR) ^ 1) * 8192)) = pk0;                           \
      *reinterpret_cast<u64*>(pW + (((CUR) ^ 1) * 8192 + 2048)) = pk1;                    \
    }                                                                                     \
    __syncthreads(); /* barrier B: DMA drained + P written */                             \
  }

  for (int it = 0; it < 32; ++it) {
    ATTN_ITER(2 * it, 0, kfrA, kfrB)
    ATTN_ITER(2 * it + 1, 1, kfrB, kfrA)
  }
#undef ATTN_ITER

  // ---- row sums: reduce over l4 groups; publish per-(kw,thf) strip sums ----
  float* lred = (float*)v_lds;  // [4 kw][64 tok]; v_lds dead after final barrier
#pragma unroll
  for (int mt = 0; mt < 2; ++mt) {
    lsum[mt] += __shfl_xor(lsum[mt], 16, 64);
    lsum[mt] += __shfl_xor(lsum[mt], 32, 64);
  }
  if (l4 == 0) {
#pragma unroll
    for (int mt = 0; mt < 2; ++mt) lred[kw * 64 + thf * 32 + mt * 16 + l15] = lsum[mt];
  }
  __syncthreads();

  const float g = gamma[0];
  float linv[8];
#pragma unroll
  for (int mt = 0; mt < 2; ++mt)
#pragma unroll
    for (int r = 0; r < 4; ++r) {
      int tok = thf * 32 + mt * 16 + l4 * 4 + r;
      linv[mt * 4 + r] =
          1.0f / (lred[tok] + lred[64 + tok] + lred[128 + tok] + lred[192 + tok]);
    }
  // ---- epilogue: out = gamma * acc / l + x ----
#pragma unroll
  for (int mt = 0; mt < 2; ++mt) {
#pragma unroll
    for (int nt = 0; nt < 4; ++nt) {
      int ch = chq * 64 + nt * 16 + l15;
      size_t idx = ((size_t)(b * 256 + ch)) * 16384 + t0 + thf * 32 + mt * 16 + l4 * 4;
      float4 xr = *reinterpret_cast<const float4*>(x + idx);
      float4 o;
      o.x = g * acc[mt][nt][0] * linv[mt * 4 + 0] + xr.x;
      o.y = g * acc[mt][nt][1] * linv[mt * 4 + 1] + xr.y;
      o.z = g * acc[mt][nt][2] * linv[mt * 4 + 2] + xr.z;
      o.w = g * acc[mt][nt][3] * linv[mt * 4 + 3] + xr.w;
      *reinterpret_cast<float4*>(out + idx) = o;
    }
  }
}

// ---------------------------------------------------------------------------
extern "C" void kernel_launch(void* const* d_in, const int* in_sizes, int n_in,
                              void* d_out, int out_size, void* d_ws, size_t ws_size,
                              hipStream_t stream) {
  const float* x = (const float*)d_in[0];
  const float* Wq = (const float*)d_in[1];
  const float* bq = (const float*)d_in[2];
  const float* Wk = (const float*)d_in[3];
  const float* bk = (const float*)d_in[4];
  const float* Wv = (const float*)d_in[5];
  const float* bv = (const float*)d_in[6];
  const float* gamma = (const float*)d_in[7];
  float* out = (float*)d_out;

  char* ws = (char*)d_ws;
  u16* Qb = (u16*)ws;                                // 2 MB  : [2][16384][32]
  u16* Kt = (u16*)(ws + (2u << 20));                 // 512 KB: [2][4096][32]
  u16* Vb = (u16*)(ws + (2u << 20) + (512u << 10));  // 4 MB  : [2][256][4096]

  proj_kernel<<<dim3(768), 256, 0, stream>>>(x, Wq, bq, Wk, bk, Wv, bv, Qb, Kt, Vb);
  attn_kernel<<<dim3(512), 512, 0, stream>>>(Qb, Kt, Vb, x, gamma, out);
}